// Round 18
// baseline (658.921 us; speedup 1.0000x reference)
//
#include <hip/hip_runtime.h>
#include <hip/hip_fp16.h>
#include <math.h>

#define NPTS 8192
#define KNB  16
#define C1   64
#define C2   128
#define NEG  0.2f
#define VEPS 1e-6f
#define NCH  32
#define CHSZ (NPTS/NCH)   // 256

// ======================= Morton reorder (exact permutation) =======================
__device__ __forceinline__ unsigned long long expand10(unsigned v) {
    unsigned long long r = v & 0x3FFu;
    r = (r | (r << 16)) & 0x030000FFULL;
    r = (r | (r <<  8)) & 0x0300F00FULL;
    r = (r | (r <<  4)) & 0x030C30C3ULL;
    r = (r | (r <<  2)) & 0x09249249ULL;
    return r;
}

__global__ __launch_bounds__(256) void keys_kernel(const float* __restrict__ x,
                                                   unsigned long long* __restrict__ keys)
{
    const int i = blockIdx.x * 256 + threadIdx.x;
    auto cell = [](float v) -> unsigned {
        float t = (v + 6.f) * (1024.f / 12.f);
        int c = (int)t;
        c = c < 0 ? 0 : (c > 1023 ? 1023 : c);
        return (unsigned)c;
    };
    const unsigned long long m = expand10(cell(x[3*i+0]))
                               | (expand10(cell(x[3*i+1])) << 1)
                               | (expand10(cell(x[3*i+2])) << 2);
    keys[i] = (m << 13) | (unsigned long long)i;
}

__global__ __launch_bounds__(256) void rank_zero(int* __restrict__ rk)
{
    rk[blockIdx.x * 256 + threadIdx.x] = 0;
}

__global__ __launch_bounds__(256) void rank_part(const unsigned long long* __restrict__ keys,
                                                 int* __restrict__ rk)
{
    __shared__ unsigned long long sk[1024];
    const int slice = blockIdx.x & 7;
    const int qg    = blockIdx.x >> 3;
    for (int j = threadIdx.x; j < 1024; j += 256) sk[j] = keys[slice*1024 + j];
    __syncthreads();
    const int i = qg*256 + threadIdx.x;
    const unsigned long long mine = keys[i];
    int r = 0;
    for (int j = 0; j < 1024; j += 4)
        r += (int)(sk[j] < mine) + (int)(sk[j+1] < mine)
           + (int)(sk[j+2] < mine) + (int)(sk[j+3] < mine);
    atomicAdd(&rk[i], r);
}

__global__ __launch_bounds__(256) void rank_scatter(const int* __restrict__ rk,
                                                    const float* __restrict__ x,
                                                    float* __restrict__ xp,
                                                    int* __restrict__ perm)
{
    const int i = blockIdx.x * 256 + threadIdx.x;
    const int r = rk[i];
    perm[r] = i;
    xp[3*r+0] = x[3*i+0]; xp[3*r+1] = x[3*i+1]; xp[3*r+2] = x[3*i+2];
}

// ======================= KNN prep: tight own-chunk threshold (4-way split) ======
__global__ __launch_bounds__(256) void ownthr_kernel(const float* __restrict__ xp,
                                                     float* __restrict__ gthr)
{
    __shared__ __align__(16) float4 cpt[CHSZ];    // 4 KB
    __shared__ float lists[4][16][64];            // 16 KB, lane-contiguous
    const int tid = threadIdx.x;
    const int lq  = tid & 63;
    const int sl  = tid >> 6;
    const int blkq0 = blockIdx.x * 64;            // grid 128
    const int chunk = blkq0 >> 8;
    const int j0    = chunk * CHSZ;

    for (int j = tid; j < CHSZ; j += 256)
        cpt[j] = make_float4(xp[3*(j0+j)+0], xp[3*(j0+j)+1], xp[3*(j0+j)+2], 0.f);
    __syncthreads();

    const int q    = blkq0 + lq;
    const int qloc = q - j0;
    const float qx = cpt[qloc].x, qy = cpt[qloc].y, qz = cpt[qloc].z;

    float bd[16];
#pragma unroll
    for (int r = 0; r < 16; ++r) bd[r] = __builtin_inff();
    for (int j = sl*64; j < sl*64 + 64; ++j) {
        const float4 p = cpt[j];
        const float dx = qx - p.x, dy = qy - p.y, dz = qz - p.z;
        const float d2 = fmaf(dx, dx, fmaf(dy, dy, dz*dz));
        if (d2 < bd[15]) {
#pragma unroll
            for (int p2 = 15; p2 > 0; --p2) {
                const bool sh = d2 < bd[p2-1];
                const bool pl = d2 < bd[p2];
                bd[p2] = sh ? bd[p2-1] : (pl ? d2 : bd[p2]);
            }
            if (d2 < bd[0]) bd[0] = d2;
        }
    }
#pragma unroll
    for (int r = 0; r < 16; ++r) lists[sl][r][lq] = bd[r];
    __syncthreads();

    if (tid < 64) {
        int h0 = 0, h1 = 0, h2 = 0, h3 = 0;
        float best = __builtin_inff();
        for (int r = 0; r < 16; ++r) {
            const float v0 = lists[0][h0][lq];
            const float v1 = lists[1][h1][lq];
            const float v2 = lists[2][h2][lq];
            const float v3 = lists[3][h3][lq];
            best = v0; int bc = 0;
            if (v1 < best) { best = v1; bc = 1; }
            if (v2 < best) { best = v2; bc = 2; }
            if (v3 < best) { best = v3; bc = 3; }
            if      (bc == 0) ++h0;
            else if (bc == 1) ++h1;
            else if (bc == 2) ++h2;
            else              ++h3;
        }
        gthr[q] = best * 1.0002f;   // conservative upper bound incl. fp margin
    }
}

__global__ __launch_bounds__(256) void aabb_kernel(const float* __restrict__ xp,
                                                   float* __restrict__ gaabb)
{
    __shared__ float wred[4][6];
    const int chunk = blockIdx.x;
    const int tid = threadIdx.x;
    const int j = chunk * CHSZ + tid;
    float mnx = xp[3*j+0], mny = xp[3*j+1], mnz = xp[3*j+2];
    float mxx = mnx, mxy = mny, mxz = mnz;
    for (int off = 32; off > 0; off >>= 1) {
        mnx = fminf(mnx, __shfl_down(mnx, off));
        mny = fminf(mny, __shfl_down(mny, off));
        mnz = fminf(mnz, __shfl_down(mnz, off));
        mxx = fmaxf(mxx, __shfl_down(mxx, off));
        mxy = fmaxf(mxy, __shfl_down(mxy, off));
        mxz = fmaxf(mxz, __shfl_down(mxz, off));
    }
    if ((tid & 63) == 0) {
        const int w = tid >> 6;
        wred[w][0]=mnx; wred[w][1]=mny; wred[w][2]=mnz;
        wred[w][3]=mxx; wred[w][4]=mxy; wred[w][5]=mxz;
    }
    __syncthreads();
    if (tid == 0) {
        float a0=wred[0][0], a1=wred[0][1], a2=wred[0][2];
        float a3=wred[0][3], a4=wred[0][4], a5=wred[0][5];
        for (int w = 1; w < 4; ++w) {
            a0=fminf(a0,wred[w][0]); a1=fminf(a1,wred[w][1]); a2=fminf(a2,wred[w][2]);
            a3=fmaxf(a3,wred[w][3]); a4=fmaxf(a4,wred[w][4]); a5=fmaxf(a5,wred[w][5]);
        }
        gaabb[chunk*8+0]=a0; gaabb[chunk*8+1]=a1; gaabb[chunk*8+2]=a2;
        gaabb[chunk*8+3]=a3; gaabb[chunk*8+4]=a4; gaabb[chunk*8+5]=a5;
    }
}

// ======================= KNN phase 1: per-chunk top-16 (wave-pruned) ============
__global__ __launch_bounds__(256) void knn_part(const float* __restrict__ x,
                                                const float* __restrict__ gthr,
                                                const float* __restrict__ gaabb,
                                                unsigned long long* __restrict__ parts)
{
    __shared__ __align__(16) float4 cpt[4 * CHSZ];        // per-wave copies, 16 KB
    __shared__ unsigned long long sbuf[256 * 9];          // 18.4 KB, stride 9

    const int tid   = threadIdx.x;
    const int wv    = tid >> 6;
    const int lane  = tid & 63;
    const int chunk = blockIdx.x & (NCH - 1);
    const int qg    = blockIdx.x >> 5;
    const int j0    = chunk * CHSZ;
    const int q     = qg * 256 + tid;

    const float qx = x[3*q+0], qy = x[3*q+1], qz = x[3*q+2];
    float thrF = gthr[q];

    {   // conservative chunk-skip: f32 AABB min-dist lower bound (x0.9998) vs thr
        const float dx = fmaxf(0.f, fmaxf(gaabb[chunk*8+0] - qx, qx - gaabb[chunk*8+3]));
        const float dy = fmaxf(0.f, fmaxf(gaabb[chunk*8+1] - qy, qy - gaabb[chunk*8+4]));
        const float dz = fmaxf(0.f, fmaxf(gaabb[chunk*8+2] - qz, qz - gaabb[chunk*8+5]));
        const float lb = fmaf(dx, dx, fmaf(dy, dy, dz*dz)) * 0.9998f;
        if (__all(lb > thrF)) {
#pragma unroll
            for (int r = 0; r < 16; ++r)
                parts[((size_t)chunk * KNB + r) * NPTS + q] = ~0ull;
            return;   // wave-uniform exit; kernel has no __syncthreads
        }
    }

    float4* wcpt = cpt + wv * CHSZ;
#pragma unroll
    for (int s = 0; s < 4; ++s) {
        const int j = lane + 64*s;
        wcpt[j] = make_float4(x[3*(j0+j)+0], x[3*(j0+j)+1], x[3*(j0+j)+2], 0.f);
    }

    unsigned long long bd[16];
#pragma unroll
    for (int r = 0; r < 16; ++r) bd[r] = ~0ull;
    int cnt = 0;
    unsigned long long* mybuf = sbuf + tid * 9;

    auto flush = [&]() {
#pragma unroll
        for (int s = 0; s < 8; ++s) {
            if (s < cnt) {
                const unsigned long long k = mybuf[s];
                if (k < bd[15]) {
#pragma unroll
                    for (int p2 = 15; p2 > 0; --p2) {
                        const bool sh = k < bd[p2-1];
                        const bool pl = k < bd[p2];
                        bd[p2] = sh ? bd[p2-1] : (pl ? k : bd[p2]);
                    }
                    if (k < bd[0]) bd[0] = k;
                }
            }
        }
        cnt = 0;
        if (bd[15] != ~0ull) {
            const double dub = __longlong_as_double((long long)(bd[15] | 8191ull));
            thrF = fminf(thrF, (float)dub * 1.0001f);
        }
    };

    for (int jj = 0; jj < CHSZ; jj += 4) {
        const float4 p0 = wcpt[jj+0];
        const float4 p1 = wcpt[jj+1];
        const float4 p2 = wcpt[jj+2];
        const float4 p3 = wcpt[jj+3];
#pragma unroll
        for (int u = 0; u < 4; ++u) {
            const float4 p = (u==0) ? p0 : (u==1) ? p1 : (u==2) ? p2 : p3;
            const float dx = qx - p.x, dy = qy - p.y, dz = qz - p.z;
            const float d2f = fmaf(dx, dx, fmaf(dy, dy, dz*dz));
            if (d2f <= thrF) {
                const double ddx = (double)dx, ddy = (double)dy, ddz = (double)dz;
                const double d2 = ddx*ddx + ddy*ddy + ddz*ddz;
                const unsigned long long key =
                    (((unsigned long long)__double_as_longlong(d2)) & ~8191ull)
                    | (unsigned long long)(j0 + jj + u);
                if (key < bd[15]) { mybuf[cnt] = key; ++cnt; }
            }
        }
        if (__any(cnt >= 5)) flush();
    }
    flush();

#pragma unroll
    for (int r = 0; r < 16; ++r)
        parts[((size_t)chunk * KNB + r) * NPTS + q] = bd[r];
}

// ======================= KNN phase 2: 32-way sorted merge =======================
__global__ __launch_bounds__(256) void knn_merge(const unsigned long long* __restrict__ parts,
                                                 int* __restrict__ idx_out)
{
    __shared__ unsigned char heads[256][NCH];
    const int tid = threadIdx.x;
    const int q = blockIdx.x * 256 + tid;
    unsigned char* h = heads[tid];
#pragma unroll
    for (int c = 0; c < NCH; ++c) h[c] = 0;
    for (int r = 0; r < KNB; ++r) {
        unsigned long long best = ~0ull; int bc = 0;
#pragma unroll
        for (int c = 0; c < NCH; ++c) {
            const unsigned long long k = parts[((size_t)c * KNB + h[c]) * NPTS + q];
            if (k < best) { best = k; bc = c; }
        }
        h[bc]++;
        idx_out[q*KNB + r] = (int)(best & 8191ull);
    }
}

// ======================= prep: Scol1/ScolU1 + Bcat_t = [W_t | W_t@U_t] ==========
__global__ __launch_bounds__(256) void prep_kernel(const float* __restrict__ kW,
                                                   const float* __restrict__ kU,
                                                   float* __restrict__ scol,
                                                   float* __restrict__ bcat)
{
    __shared__ float sW[64*64];
    __shared__ float sS[64];
    const int t = blockIdx.x;
    const int tid = threadIdx.x;
    if (t == 0) {
        for (int e = tid; e < 64*64; e += 256) sW[e] = kW[e];
        __syncthreads();
        if (tid < 64) {
            float s = 0.f;
            for (int j = 0; j < 64; ++j) s += sW[j*64 + tid];
            sS[tid] = s;
        }
        __syncthreads();
        if (tid < 64) {
            float s2 = 0.f;
            for (int j = 0; j < 64; ++j) s2 = fmaf(sS[j], kU[j*64 + tid], s2);
            scol[tid]      = sS[tid];
            scol[64 + tid] = s2;
        }
    } else {
        const float* W = kW + t*4096;
        const float* U = kU + t*4096;
        for (int e = tid; e < 64*64; e += 256) sW[e] = W[e];
        __syncthreads();
        float* B = bcat + (size_t)(t-1)*64*128;
        for (int o = tid; o < 64*64; o += 256) {
            const int j = o >> 6, c = o & 63;
            float s = 0.f;
            for (int l = 0; l < 64; ++l) s = fmaf(sW[j*64 + l], U[l*64 + c], s);
            B[j*128 + c]      = sW[j*64 + c];
            B[j*128 + 64 + c] = s;
        }
    }
}

// ======================= step1: rank-1 closed form =======================
__global__ __launch_bounds__(256) void step1_kernel(const float* __restrict__ xp,
                                                    const int* __restrict__ idxs,
                                                    const float* __restrict__ scol,
                                                    float* __restrict__ R1)
{
    const int pt = blockIdx.x * 256 + threadIdx.x;
    float mx0 = 0.f, mx1 = 0.f, mx2 = 0.f;
#pragma unroll
    for (int k = 0; k < KNB; ++k) {
        const int id = idxs[pt*KNB + k];
        mx0 += xp[3*id+0]; mx1 += xp[3*id+1]; mx2 += xp[3*id+2];
    }
    const float inv = 1.0f / KNB;
    mx0 *= inv; mx1 *= inv; mx2 *= inv;
    const float S2 = mx0*mx0 + mx1*mx1 + mx2*mx2;
    float* op = R1 + (size_t)pt * 192;
    for (int c = 0; c < 64; ++c) {
        const float sc = scol[c], su = scol[64 + c];
        const float dt = S2 * sc * su;
        const float dn = S2 * su * su;
        const float m  = (dt < 0.f) ? 0.8f * dt / (dn + VEPS) : 0.f;
        const float rc = fmaf(-m, su, sc);
        op[c]       = mx0 * rc;
        op[64 + c]  = mx1 * rc;
        op[128 + c] = mx2 * rc;
    }
}

// ======================= zgemm: YwZ = R @ Bcat (K=64, N=128), f32 out ============
#define FMA4(ar, b0, b1, b2, b3, acc) \
    acc.x = fmaf(ar.x,b0.x, fmaf(ar.y,b1.x, fmaf(ar.z,b2.x, fmaf(ar.w,b3.x, acc.x)))); \
    acc.y = fmaf(ar.x,b0.y, fmaf(ar.y,b1.y, fmaf(ar.z,b2.y, fmaf(ar.w,b3.y, acc.y)))); \
    acc.z = fmaf(ar.x,b0.z, fmaf(ar.y,b1.z, fmaf(ar.z,b2.z, fmaf(ar.w,b3.z, acc.z)))); \
    acc.w = fmaf(ar.x,b0.w, fmaf(ar.y,b1.w, fmaf(ar.z,b2.w, fmaf(ar.w,b3.w, acc.w))));

template<bool HALF_OUT>
__global__ __launch_bounds__(256) void zgemm_kernel(const float* __restrict__ R,
                                                    const float* __restrict__ Bcat,
                                                    float* __restrict__ YwZf,
                                                    __half* __restrict__ YwZh)
{
    constexpr int SA = 68;
    __shared__ __align__(16) float sA[64*SA];
    __shared__ __align__(16) float sB[64*128];
    const int tid = threadIdx.x;
    const size_t row0 = (size_t)blockIdx.x * 64;

    for (int e4 = tid; e4 < 1024; e4 += 256) {
        const int r = e4 >> 4, c4 = (e4 & 15) * 4;
        *reinterpret_cast<float4*>(sA + r*SA + c4) =
            *reinterpret_cast<const float4*>(R + (row0 + r)*64 + c4);
    }
    for (int e4 = tid; e4 < 2048; e4 += 256) {
        const int j = e4 >> 5, c4 = (e4 & 31) * 4;
        *reinterpret_cast<float4*>(sB + j*128 + c4) =
            *reinterpret_cast<const float4*>(Bcat + j*128 + c4);
    }
    __syncthreads();

    const int rg = tid >> 5;
    const int d  = (tid & 31) * 4;
    float4 acc[8];
#pragma unroll
    for (int i = 0; i < 8; ++i) acc[i] = make_float4(0,0,0,0);
    for (int c = 0; c < 64; c += 4) {
        const float4 b0 = *reinterpret_cast<const float4*>(sB + (c+0)*128 + d);
        const float4 b1 = *reinterpret_cast<const float4*>(sB + (c+1)*128 + d);
        const float4 b2 = *reinterpret_cast<const float4*>(sB + (c+2)*128 + d);
        const float4 b3 = *reinterpret_cast<const float4*>(sB + (c+3)*128 + d);
        float4 a;
        a = *reinterpret_cast<const float4*>(sA + (rg*8+0)*SA + c); FMA4(a,b0,b1,b2,b3,acc[0]);
        a = *reinterpret_cast<const float4*>(sA + (rg*8+1)*SA + c); FMA4(a,b0,b1,b2,b3,acc[1]);
        a = *reinterpret_cast<const float4*>(sA + (rg*8+2)*SA + c); FMA4(a,b0,b1,b2,b3,acc[2]);
        a = *reinterpret_cast<const float4*>(sA + (rg*8+3)*SA + c); FMA4(a,b0,b1,b2,b3,acc[3]);
        a = *reinterpret_cast<const float4*>(sA + (rg*8+4)*SA + c); FMA4(a,b0,b1,b2,b3,acc[4]);
        a = *reinterpret_cast<const float4*>(sA + (rg*8+5)*SA + c); FMA4(a,b0,b1,b2,b3,acc[5]);
        a = *reinterpret_cast<const float4*>(sA + (rg*8+6)*SA + c); FMA4(a,b0,b1,b2,b3,acc[6]);
        a = *reinterpret_cast<const float4*>(sA + (rg*8+7)*SA + c); FMA4(a,b0,b1,b2,b3,acc[7]);
    }
    if (HALF_OUT) {
        __half* op = YwZh + (row0 + rg*8)*128 + d;
#pragma unroll
        for (int i = 0; i < 8; ++i) {
            __half2 lo = __floats2half2_rn(acc[i].x, acc[i].y);
            __half2 hi = __floats2half2_rn(acc[i].z, acc[i].w);
            *reinterpret_cast<__half2*>(op + i*128)     = lo;
            *reinterpret_cast<__half2*>(op + i*128 + 2) = hi;
        }
    } else {
        float* op = YwZf + (row0 + rg*8)*128 + d;
#pragma unroll
        for (int i = 0; i < 8; ++i)
            *reinterpret_cast<float4*>(op + i*128) = acc[i];
    }
}

// ======================= gather steps 2,3 (LDS-buf, sliding window, f32) ========
template<int PINP, int TT>
__global__ __launch_bounds__(256) void gather_kernel(
    const float* __restrict__ xp, const int* __restrict__ idxs,
    const float* __restrict__ yz,
    float* __restrict__ Rout,
    int ppb)
{
    constexpr int PCW = PINP * 128;
    constexpr int NSL = PCW / 4;
    constexpr int TC  = TT * 64;

    __shared__ __align__(16) float buf[TT * 128];
    __shared__ int   sIds[KNB];
    __shared__ float sXg[KNB*3];
    __shared__ float pdt[4][64], pdn[4][64], msc[64];

    const int tid   = threadIdx.x;
    const int slots = gridDim.x >> 3;
    const int xcd   = blockIdx.x & 7;
    const int slot  = blockIdx.x >> 3;
    const int base  = xcd * slots * ppb;

    for (int pi = 0; pi < ppb; ++pi) {
        const int pt = base + pi * slots + slot;
        if (tid < KNB) {
            const int id = idxs[pt*KNB + tid];
            sIds[tid] = id;
            sXg[tid*3+0] = xp[3*id+0];
            sXg[tid*3+1] = xp[3*id+1];
            sXg[tid*3+2] = xp[3*id+2];
        }
        __syncthreads();

        float xr[KNB*3];
#pragma unroll
        for (int e = 0; e < KNB*3; ++e) xr[e] = sXg[e];

        for (int sl = tid; sl < NSL; sl += 256) {
            const int b  = sl >> 5;
            const int cc = (sl & 31) * 4;
            float4 s0 = {0,0,0,0}, s1 = s0, s2 = s0;
#pragma unroll
            for (int k = 0; k < KNB; ++k) {
                const float4 val = *reinterpret_cast<const float4*>(
                    yz + (size_t)sIds[k]*PCW + b*128 + cc);
                const float xa = xr[k*3+0], xb = xr[k*3+1], xc = xr[k*3+2];
                s0.x=fmaf(xa,val.x,s0.x); s0.y=fmaf(xa,val.y,s0.y);
                s0.z=fmaf(xa,val.z,s0.z); s0.w=fmaf(xa,val.w,s0.w);
                s1.x=fmaf(xb,val.x,s1.x); s1.y=fmaf(xb,val.y,s1.y);
                s1.z=fmaf(xb,val.z,s1.z); s1.w=fmaf(xb,val.w,s1.w);
                s2.x=fmaf(xc,val.x,s2.x); s2.y=fmaf(xc,val.y,s2.y);
                s2.z=fmaf(xc,val.z,s2.z); s2.w=fmaf(xc,val.w,s2.w);
            }
            const float inv = 1.0f / KNB;
            s0.x*=inv; s0.y*=inv; s0.z*=inv; s0.w*=inv;
            s1.x*=inv; s1.y*=inv; s1.z*=inv; s1.w*=inv;
            s2.x*=inv; s2.y*=inv; s2.z*=inv; s2.w*=inv;
            *reinterpret_cast<float4*>(buf + (0*PINP + b)*128 + cc) = s0;
            *reinterpret_cast<float4*>(buf + (1*PINP + b)*128 + cc) = s1;
            *reinterpret_cast<float4*>(buf + (2*PINP + b)*128 + cc) = s2;
        }
        __syncthreads();
        {
            const int c = tid & 63, g = tid >> 6;
            float dt = 0.f, dn = 0.f;
            for (int t = g; t < TT; t += 4) {
                const float vv = buf[t*128 + c], dd = buf[t*128 + 64 + c];
                dt = fmaf(vv, dd, dt); dn = fmaf(dd, dd, dn);
            }
            pdt[g][c] = dt; pdn[g][c] = dn;
        }
        __syncthreads();
        if (tid < 64) {
            const float dt = pdt[0][tid]+pdt[1][tid]+pdt[2][tid]+pdt[3][tid];
            const float dn = pdn[0][tid]+pdn[1][tid]+pdn[2][tid]+pdn[3][tid];
            msc[tid] = (dt < 0.f) ? 0.8f * dt / (dn + VEPS) : 0.f;
        }
        __syncthreads();
        {
            float* op = Rout + (size_t)pt * TC;
            for (int e = tid; e < TC; e += 256) {
                const int t = e >> 6, c = e & 63;
                op[e] = fmaf(-msc[c], buf[t*128 + 64 + c], buf[t*128 + c]);
            }
        }
        __syncthreads();
    }
}

// ======================= gather step 4: channel-split, fp16 source =============
#define FMAQS(acc, s, val) \
    acc.x = fmaf(s, val.x, acc.x); acc.y = fmaf(s, val.y, acc.y); \
    acc.z = fmaf(s, val.z, acc.z); acc.w = fmaf(s, val.w, acc.w);

__device__ __forceinline__ float4 load_h4(const __half* p) {
    const float2 raw = *reinterpret_cast<const float2*>(p);   // one 8B load
    const __half2 h0 = *reinterpret_cast<const __half2*>(&raw.x);
    const __half2 h1 = *reinterpret_cast<const __half2*>(&raw.y);
    const float2 f0 = __half22float2(h0);
    const float2 f1 = __half22float2(h1);
    return make_float4(f0.x, f0.y, f1.x, f1.y);
}

__global__ __launch_bounds__(256) void gather4_kernel(
    const float* __restrict__ xp, const int* __restrict__ idxs,
    const __half* __restrict__ yz,     // NPTS x 3456 (fp16)
    const float* __restrict__ w4,
    float* __restrict__ hv, float* __restrict__ gpart,
    int ppb)
{
    constexpr int TT = 81;
    constexpr int CH = 32;
    constexpr int SB = 68;
    constexpr int NG = (TT*CH + 255) / 256;   // 11

    __shared__ __align__(16) float buf[TT * SB];
    __shared__ int   sIds[KNB];
    __shared__ float sXg[KNB*3];
    __shared__ float pdt[27][33], pdn[27][33];
    __shared__ float msc[CH];

    const int tid   = threadIdx.x;
    const int xcd   = blockIdx.x & 7;
    const int r2    = blockIdx.x >> 3;
    const int half  = r2 & 1;
    const int slot  = r2 >> 1;
    const int slots = gridDim.x >> 4;          // 128
    const int base0 = xcd * slots * ppb;
    const int c0    = half * CH;
    const int eff   = xcd * slots + slot;      // < 1024

    const int ub  = tid >> 3;
    const int ucq = tid & 7;
    const bool act = (ub < 27);
    const int srcV = ub*128 + c0 + ucq*4;
    const int srcD = srcV + 64;

    float gacc[NG];
#pragma unroll
    for (int i = 0; i < NG; ++i) gacc[i] = 0.f;

    for (int pi = 0; pi < ppb; ++pi) {
        const int pt = base0 + pi * slots + slot;
        if (tid < KNB) {
            const int id = idxs[pt*KNB + tid];
            sIds[tid] = id;
            sXg[tid*3+0] = xp[3*id+0];
            sXg[tid*3+1] = xp[3*id+1];
            sXg[tid*3+2] = xp[3*id+2];
        }
        __syncthreads();

        if (act) {
            float4 vA[3], dA[3];
#pragma unroll
            for (int a = 0; a < 3; ++a) { vA[a] = make_float4(0,0,0,0); dA[a] = vA[a]; }
#pragma unroll
            for (int k = 0; k < KNB; ++k) {
                const __half* rowp = yz + (size_t)sIds[k]*3456;
                const float4 vq = load_h4(rowp + srcV);
                const float4 dq = load_h4(rowp + srcD);
                const float xa = sXg[k*3+0], xb = sXg[k*3+1], xc = sXg[k*3+2];
                FMAQS(vA[0], xa, vq) FMAQS(vA[1], xb, vq) FMAQS(vA[2], xc, vq)
                FMAQS(dA[0], xa, dq) FMAQS(dA[1], xb, dq) FMAQS(dA[2], xc, dq)
            }
            const float inv = 1.0f / KNB;
            float4 dt4 = make_float4(0,0,0,0), dn4 = dt4;
#pragma unroll
            for (int a = 0; a < 3; ++a) {
                vA[a].x*=inv; vA[a].y*=inv; vA[a].z*=inv; vA[a].w*=inv;
                dA[a].x*=inv; dA[a].y*=inv; dA[a].z*=inv; dA[a].w*=inv;
                dt4.x = fmaf(vA[a].x, dA[a].x, dt4.x);
                dt4.y = fmaf(vA[a].y, dA[a].y, dt4.y);
                dt4.z = fmaf(vA[a].z, dA[a].z, dt4.z);
                dt4.w = fmaf(vA[a].w, dA[a].w, dt4.w);
                dn4.x = fmaf(dA[a].x, dA[a].x, dn4.x);
                dn4.y = fmaf(dA[a].y, dA[a].y, dn4.y);
                dn4.z = fmaf(dA[a].z, dA[a].z, dn4.z);
                dn4.w = fmaf(dA[a].w, dA[a].w, dn4.w);
                float* bp = buf + (a*27 + ub)*SB;
                *reinterpret_cast<float4*>(bp + ucq*4)      = vA[a];
                *reinterpret_cast<float4*>(bp + 32 + ucq*4) = dA[a];
            }
            pdt[ub][ucq*4+0] = dt4.x; pdt[ub][ucq*4+1] = dt4.y;
            pdt[ub][ucq*4+2] = dt4.z; pdt[ub][ucq*4+3] = dt4.w;
            pdn[ub][ucq*4+0] = dn4.x; pdn[ub][ucq*4+1] = dn4.y;
            pdn[ub][ucq*4+2] = dn4.z; pdn[ub][ucq*4+3] = dn4.w;
        }
        __syncthreads();
        if (tid < CH) {
            float dt = 0.f, dn = 0.f;
#pragma unroll
            for (int b2 = 0; b2 < 27; ++b2) { dt += pdt[b2][tid]; dn += pdn[b2][tid]; }
            msc[tid] = (dt < 0.f) ? 0.8f * dt / (dn + VEPS) : 0.f;
        }
        __syncthreads();
#pragma unroll
        for (int i = 0; i < NG; ++i) {
            const int e = i*256 + tid;
            if (e < TT*CH) {
                const int t = e >> 5, cc = e & 31;
                const float v = fmaf(-msc[cc], buf[t*SB + 32 + cc], buf[t*SB + cc]);
                buf[t*SB + cc] = v;
                gacc[i] += v;
            }
        }
        __syncthreads();
        for (int e = tid; e < 9*CH; e += 256) {
            const int pq = e >> 5, cc = e & 31;
            const int p = pq / 3, qq = pq - 3*p;
            const int c = c0 + cc;
            float tr0=0,tr1=0,tr2=0,tr3=0,tr4=0,tr5=0;
#pragma unroll
            for (int r = 0; r < 3; ++r) {
                tr0 += buf[(r*36 + p*3 + qq )*SB + cc];
                tr1 += buf[(r*30 + p*9 + qq )*SB + cc];
                tr2 += buf[(r*28 + p*9 + qq*3)*SB + cc];
                tr3 += buf[(p*27 + r*12 + qq )*SB + cc];
                tr4 += buf[(p*27 + r*10 + qq*3)*SB + cc];
                tr5 += buf[(p*27 + qq*9 + r*4 )*SB + cc];
            }
            hv[(size_t)pt*576 + pq*64 + c] =
                  w4[0*C2 + c]*tr0 + w4[1*C2 + c]*tr1 + w4[2*C2 + c]*tr2
                + w4[3*C2 + c]*tr3 + w4[4*C2 + c]*tr4 + w4[5*C2 + c]*tr5;
        }
        __syncthreads();
    }
    float* gp = gpart + (size_t)eff * 5184;
#pragma unroll
    for (int i = 0; i < NG; ++i) {
        const int e = i*256 + tid;
        if (e < TT*CH) {
            const int t = e >> 5, cc = e & 31;
            gp[t*64 + c0 + cc] = gacc[i];
        }
    }
}

// ======================= g reduction (1024 parts) =======================
__global__ __launch_bounds__(256) void reduce_g_kernel(const float* __restrict__ gpart,
                                                       float* __restrict__ g)
{
    __shared__ float red[256];
    const int el = threadIdx.x & 15, pg = threadIdx.x >> 4;
    const int e = blockIdx.x * 16 + el;
    float s = 0.f;
    for (int p = pg; p < 1024; p += 16) s += gpart[(size_t)p * (81*C1) + e];
    red[threadIdx.x] = s;
    __syncthreads();
    for (int st = 8; st > 0; st >>= 1) {
        if (pg < st) red[el + 16*pg] += red[el + 16*(pg+st)];
        __syncthreads();
    }
    if (pg == 0) g[e] = red[el] * (1.0f/NPTS);
}

// ======================= hg + hgW precompute =======================
__global__ __launch_bounds__(256) void hgw_kernel(const float* __restrict__ g,
                                                  const float* __restrict__ w4,
                                                  const float* __restrict__ cW,
                                                  float* __restrict__ hgW)
{
    __shared__ float gs[81*C1];
    __shared__ float hg[9*C1];
    const int tid = threadIdx.x;
    for (int e = tid; e < 81*C1; e += 256) gs[e] = g[e];
    __syncthreads();
    for (int e = tid; e < 9*C1; e += 256) {
        const int pq = e >> 6, c = e & 63;
        const int p = pq / 3, qq = pq - 3*p;
        float tr0=0,tr1=0,tr2=0,tr3=0,tr4=0,tr5=0;
#pragma unroll
        for (int r = 0; r < 3; ++r) {
            tr0 += gs[(r*36 + p*3 + qq ) * C1 + c];
            tr1 += gs[(r*30 + p*9 + qq ) * C1 + c];
            tr2 += gs[(r*28 + p*9 + qq*3) * C1 + c];
            tr3 += gs[(p*27 + r*12 + qq ) * C1 + c];
            tr4 += gs[(p*27 + r*10 + qq*3) * C1 + c];
            tr5 += gs[(p*27 + qq*9 + r*4 ) * C1 + c];
        }
        hg[e] = w4[0*C2 + 64 + c]*tr0 + w4[1*C2 + 64 + c]*tr1 + w4[2*C2 + 64 + c]*tr2
              + w4[3*C2 + 64 + c]*tr3 + w4[4*C2 + 64 + c]*tr4 + w4[5*C2 + 64 + c]*tr5;
    }
    __syncthreads();
    for (int o = tid; o < 9*C2; o += 256) {
        const int t = o >> 7, c = o & 127;
        float s = 0.f;
        for (int j = 0; j < C1; ++j) s = fmaf(hg[t*C1 + j], cW[(C1+j)*C2 + c], s);
        hgW[o] = s;
    }
}

// ======================= contraction head =======================
__global__ __launch_bounds__(256) void contract_kernel(const float* __restrict__ hv,
                                                       const float* __restrict__ hgW,
                                                       const float* __restrict__ cW,
                                                       const float* __restrict__ cU,
                                                       const float* __restrict__ w2,
                                                       const int* __restrict__ perm,
                                                       float* __restrict__ out,
                                                       int ppb)
{
    constexpr int S0 = C1 + 4;
    constexpr int SH = C2 + 4;
    __shared__ __align__(16) float h0[36*S0];
    __shared__ __align__(16) float h1[36*SH];
    __shared__ __align__(16) float h2[36*SH];
    __shared__ __align__(16) float hgs[9*C2];
    __shared__ int sPerm[4];

    const int tid = threadIdx.x;
    for (int e = tid; e < 9*C2; e += 256) hgs[e] = hgW[e];
    __syncthreads();

    const int iters = ppb >> 2;
    for (int it = 0; it < iters; ++it) {
        const int base = blockIdx.x * ppb + it * 4;
        if (tid < 4) sPerm[tid] = perm[base + tid];
        for (int e = tid; e < 4*9*C1; e += 256) {
            const int pt = e / 576, rem = e - pt*576;
            const int t = rem >> 6, c = rem & 63;
            h0[(pt*9 + t)*S0 + c] = hv[(size_t)(base+pt)*576 + rem];
        }
        __syncthreads();
        for (int u = tid; u < 9*32; u += 256) {
            const int tg = u >> 5;
            const int d  = (u & 31) * 4;
            const int r0 = tg*4;
            float4 acc0 = *reinterpret_cast<const float4*>(hgs + ((r0+0)%9)*C2 + d);
            float4 acc1 = *reinterpret_cast<const float4*>(hgs + ((r0+1)%9)*C2 + d);
            float4 acc2 = *reinterpret_cast<const float4*>(hgs + ((r0+2)%9)*C2 + d);
            float4 acc3 = *reinterpret_cast<const float4*>(hgs + ((r0+3)%9)*C2 + d);
            for (int c = 0; c < C1; c += 4) {
                const float4 a0 = *reinterpret_cast<const float4*>(h0 + (r0+0)*S0 + c);
                const float4 a1 = *reinterpret_cast<const float4*>(h0 + (r0+1)*S0 + c);
                const float4 a2 = *reinterpret_cast<const float4*>(h0 + (r0+2)*S0 + c);
                const float4 a3 = *reinterpret_cast<const float4*>(h0 + (r0+3)*S0 + c);
                const float4 b0 = *reinterpret_cast<const float4*>(cW + (c+0)*C2 + d);
                const float4 b1 = *reinterpret_cast<const float4*>(cW + (c+1)*C2 + d);
                const float4 b2 = *reinterpret_cast<const float4*>(cW + (c+2)*C2 + d);
                const float4 b3 = *reinterpret_cast<const float4*>(cW + (c+3)*C2 + d);
                FMA4(a0, b0, b1, b2, b3, acc0);
                FMA4(a1, b0, b1, b2, b3, acc1);
                FMA4(a2, b0, b1, b2, b3, acc2);
                FMA4(a3, b0, b1, b2, b3, acc3);
            }
            *reinterpret_cast<float4*>(h1 + (r0+0)*SH + d) = acc0;
            *reinterpret_cast<float4*>(h1 + (r0+1)*SH + d) = acc1;
            *reinterpret_cast<float4*>(h1 + (r0+2)*SH + d) = acc2;
            *reinterpret_cast<float4*>(h1 + (r0+3)*SH + d) = acc3;
        }
        __syncthreads();
        for (int u = tid; u < 9*32; u += 256) {
            const int tg = u >> 5;
            const int d  = (u & 31) * 4;
            const int r0 = tg*4;
            float4 acc0 = {0,0,0,0}, acc1 = acc0, acc2 = acc0, acc3 = acc0;
            for (int c = 0; c < C2; c += 4) {
                const float4 a0 = *reinterpret_cast<const float4*>(h1 + (r0+0)*SH + c);
                const float4 a1 = *reinterpret_cast<const float4*>(h1 + (r0+1)*SH + c);
                const float4 a2 = *reinterpret_cast<const float4*>(h1 + (r0+2)*SH + c);
                const float4 a3 = *reinterpret_cast<const float4*>(h1 + (r0+3)*SH + c);
                const float4 b0 = *reinterpret_cast<const float4*>(cU + (c+0)*C2 + d);
                const float4 b1 = *reinterpret_cast<const float4*>(cU + (c+1)*C2 + d);
                const float4 b2 = *reinterpret_cast<const float4*>(cU + (c+2)*C2 + d);
                const float4 b3 = *reinterpret_cast<const float4*>(cU + (c+3)*C2 + d);
                FMA4(a0, b0, b1, b2, b3, acc0);
                FMA4(a1, b0, b1, b2, b3, acc1);
                FMA4(a2, b0, b1, b2, b3, acc2);
                FMA4(a3, b0, b1, b2, b3, acc3);
            }
            *reinterpret_cast<float4*>(h2 + (r0+0)*SH + d) = acc0;
            *reinterpret_cast<float4*>(h2 + (r0+1)*SH + d) = acc1;
            *reinterpret_cast<float4*>(h2 + (r0+2)*SH + d) = acc2;
            *reinterpret_cast<float4*>(h2 + (r0+3)*SH + d) = acc3;
        }
        __syncthreads();
#pragma unroll
        for (int p2 = 0; p2 < 2; ++p2) {
            const int pair = tid + 256*p2;
            const int pt = pair >> 7, c = pair & 127;
            float dt = 0.f, dn = 0.f;
            for (int t = 0; t < 9; ++t) {
                const float vv = h1[(pt*9+t)*SH + c], dd = h2[(pt*9+t)*SH + c];
                dt = fmaf(vv, dd, dt); dn = fmaf(dd, dd, dn);
            }
            const float m = (dt < 0.f) ? 0.8f * dt / (dn + VEPS) : 0.f;
            float s = 0.f;
#pragma unroll
            for (int r = 0; r < 3; ++r) {
                const int t = r * 4;
                s += fmaf(-m, h2[(pt*9+t)*SH + c], h1[(pt*9+t)*SH + c]);
            }
            out[(size_t)sPerm[pt]*C2 + c] = w2[c] * s;
        }
        __syncthreads();
    }
}

// ======================= launcher =======================
extern "C" void kernel_launch(void* const* d_in, const int* in_sizes, int n_in,
                              void* d_out, int out_size, void* d_ws, size_t ws_size,
                              hipStream_t stream)
{
    (void)in_sizes; (void)n_in; (void)out_size; (void)ws_size;
    const float* x  = (const float*)d_in[0];
    const float* kW = (const float*)d_in[1];
    const float* kU = (const float*)d_in[2];
    const float* w4 = (const float*)d_in[3];
    const float* cW = (const float*)d_in[4];
    const float* cU = (const float*)d_in[5];
    const float* w2 = (const float*)d_in[6];
    float* out = (float*)d_out;

    char* ws = (char*)d_ws;
    size_t off = 0;
    auto alloc = [&](size_t bytes) -> void* {
        void* p = ws + off; off += (bytes + 255) & ~(size_t)255; return p;
    };
    int*   idx   = (int*)  alloc((size_t)NPTS*KNB*4);
    float* xp    = (float*)alloc((size_t)NPTS*3*4);
    unsigned long long* keys = (unsigned long long*)alloc((size_t)NPTS*8);
    int*   perm  = (int*)  alloc((size_t)NPTS*4);
    int*   rk    = (int*)  alloc((size_t)NPTS*4);
    float* gthr  = (float*)alloc((size_t)NPTS*4);
    float* gaabb = (float*)alloc((size_t)NCH*8*4);
    float* scol  = (float*)alloc(128*4);
    float* bcat  = (float*)alloc((size_t)3*64*128*4);
    float* R1    = (float*)alloc((size_t)NPTS*3*C1*4);      // hv alias (spans into YwZ2)
    float* YwZ2  = (float*)alloc((size_t)NPTS*3*C2*4);
    float* R2    = (float*)alloc((size_t)NPTS*9*C1*4);      // gpart alias (spans into YwZ3)
    float* YwZ3  = (float*)alloc((size_t)NPTS*9*C2*4);
    float* R3    = (float*)alloc((size_t)NPTS*27*C1*4);
    __half* YwZ4 = (__half*)alloc((size_t)NPTS*27*C2*2);    // 56.6 MB fp16
    float* g     = (float*)alloc((size_t)81*C1*4);
    float* hgW   = (float*)alloc((size_t)9*C2*4);

    float* hv    = R1;
    float* gpart = R2;
    unsigned long long* parts = (unsigned long long*)YwZ4;  // 33.5MB <= 56.6MB, dead before zgemm4

    keys_kernel <<<NPTS/256, 256, 0, stream>>>(x, keys);
    rank_zero   <<<NPTS/256, 256, 0, stream>>>(rk);
    rank_part   <<<256, 256, 0, stream>>>(keys, rk);
    rank_scatter<<<NPTS/256, 256, 0, stream>>>(rk, x, xp, perm);
    ownthr_kernel<<<NPTS/64, 256, 0, stream>>>(xp, gthr);
    aabb_kernel <<<NCH, 256, 0, stream>>>(xp, gaabb);
    knn_part    <<<32*NCH, 256, 0, stream>>>(xp, gthr, gaabb, parts);
    knn_merge   <<<NPTS/256, 256, 0, stream>>>(parts, idx);
    prep_kernel <<<4, 256, 0, stream>>>(kW, kU, scol, bcat);
    step1_kernel<<<NPTS/256, 256, 0, stream>>>(xp, idx, scol, R1);

    zgemm_kernel<false><<<NPTS*3/64,  256, 0, stream>>>(R1, bcat,         YwZ2, nullptr);
    gather_kernel<3, 9>  <<<2048, 256, 0, stream>>>(xp, idx, YwZ2, R2, 4);
    zgemm_kernel<false><<<NPTS*9/64,  256, 0, stream>>>(R2, bcat + 8192,  YwZ3, nullptr);
    gather_kernel<9, 27> <<<2048, 256, 0, stream>>>(xp, idx, YwZ3, R3, 4);
    zgemm_kernel<true> <<<NPTS*27/64, 256, 0, stream>>>(R3, bcat + 16384, nullptr, YwZ4);
    gather4_kernel<<<2048, 256, 0, stream>>>(xp, idx, YwZ4, w4, hv, gpart, 8);

    reduce_g_kernel<<<324, 256, 0, stream>>>(gpart, g);
    hgw_kernel<<<1, 256, 0, stream>>>(g, w4, cW, hgW);
    contract_kernel<<<1024, 256, 0, stream>>>(hv, hgW, cW, cU, w2, perm, out, 8);
}

// Round 19
// 637.763 us; speedup vs baseline: 1.0332x; 1.0332x over previous
//
#include <hip/hip_runtime.h>
#include <math.h>

#define NPTS 8192
#define KNB  16
#define C1   64
#define C2   128
#define NEG  0.2f
#define VEPS 1e-6f
#define NCH  32
#define CHSZ (NPTS/NCH)   // 256

// ======================= Morton reorder (exact permutation) =======================
__device__ __forceinline__ unsigned long long expand10(unsigned v) {
    unsigned long long r = v & 0x3FFu;
    r = (r | (r << 16)) & 0x030000FFULL;
    r = (r | (r <<  8)) & 0x0300F00FULL;
    r = (r | (r <<  4)) & 0x030C30C3ULL;
    r = (r | (r <<  2)) & 0x09249249ULL;
    return r;
}

__global__ __launch_bounds__(256) void keys_kernel(const float* __restrict__ x,
                                                   unsigned long long* __restrict__ keys)
{
    const int i = blockIdx.x * 256 + threadIdx.x;
    auto cell = [](float v) -> unsigned {
        float t = (v + 6.f) * (1024.f / 12.f);
        int c = (int)t;
        c = c < 0 ? 0 : (c > 1023 ? 1023 : c);
        return (unsigned)c;
    };
    const unsigned long long m = expand10(cell(x[3*i+0]))
                               | (expand10(cell(x[3*i+1])) << 1)
                               | (expand10(cell(x[3*i+2])) << 2);
    keys[i] = (m << 13) | (unsigned long long)i;
}

__global__ __launch_bounds__(256) void rank_zero(int* __restrict__ rk)
{
    rk[blockIdx.x * 256 + threadIdx.x] = 0;
}

__global__ __launch_bounds__(256) void rank_part(const unsigned long long* __restrict__ keys,
                                                 int* __restrict__ rk)
{
    __shared__ unsigned long long sk[1024];
    const int slice = blockIdx.x & 7;
    const int qg    = blockIdx.x >> 3;
    for (int j = threadIdx.x; j < 1024; j += 256) sk[j] = keys[slice*1024 + j];
    __syncthreads();
    const int i = qg*256 + threadIdx.x;
    const unsigned long long mine = keys[i];
    int r = 0;
    for (int j = 0; j < 1024; j += 4)
        r += (int)(sk[j] < mine) + (int)(sk[j+1] < mine)
           + (int)(sk[j+2] < mine) + (int)(sk[j+3] < mine);
    atomicAdd(&rk[i], r);
}

__global__ __launch_bounds__(256) void rank_scatter(const int* __restrict__ rk,
                                                    const float* __restrict__ x,
                                                    float* __restrict__ xp,
                                                    int* __restrict__ perm)
{
    const int i = blockIdx.x * 256 + threadIdx.x;
    const int r = rk[i];
    perm[r] = i;
    xp[3*r+0] = x[3*i+0]; xp[3*r+1] = x[3*i+1]; xp[3*r+2] = x[3*i+2];
}

// ======================= KNN prep: tight own-chunk threshold (4-way split) ======
__global__ __launch_bounds__(256) void ownthr_kernel(const float* __restrict__ xp,
                                                     float* __restrict__ gthr)
{
    __shared__ __align__(16) float4 cpt[CHSZ];    // 4 KB
    __shared__ float lists[4][16][64];            // 16 KB, lane-contiguous
    const int tid = threadIdx.x;
    const int lq  = tid & 63;
    const int sl  = tid >> 6;
    const int blkq0 = blockIdx.x * 64;            // grid 128
    const int chunk = blkq0 >> 8;
    const int j0    = chunk * CHSZ;

    for (int j = tid; j < CHSZ; j += 256)
        cpt[j] = make_float4(xp[3*(j0+j)+0], xp[3*(j0+j)+1], xp[3*(j0+j)+2], 0.f);
    __syncthreads();

    const int q    = blkq0 + lq;
    const int qloc = q - j0;
    const float qx = cpt[qloc].x, qy = cpt[qloc].y, qz = cpt[qloc].z;

    float bd[16];
#pragma unroll
    for (int r = 0; r < 16; ++r) bd[r] = __builtin_inff();
    for (int j = sl*64; j < sl*64 + 64; ++j) {
        const float4 p = cpt[j];
        const float dx = qx - p.x, dy = qy - p.y, dz = qz - p.z;
        const float d2 = fmaf(dx, dx, fmaf(dy, dy, dz*dz));
        if (d2 < bd[15]) {
#pragma unroll
            for (int p2 = 15; p2 > 0; --p2) {
                const bool sh = d2 < bd[p2-1];
                const bool pl = d2 < bd[p2];
                bd[p2] = sh ? bd[p2-1] : (pl ? d2 : bd[p2]);
            }
            if (d2 < bd[0]) bd[0] = d2;
        }
    }
#pragma unroll
    for (int r = 0; r < 16; ++r) lists[sl][r][lq] = bd[r];
    __syncthreads();

    if (tid < 64) {
        int h0 = 0, h1 = 0, h2 = 0, h3 = 0;
        float best = __builtin_inff();
        for (int r = 0; r < 16; ++r) {
            const float v0 = lists[0][h0][lq];
            const float v1 = lists[1][h1][lq];
            const float v2 = lists[2][h2][lq];
            const float v3 = lists[3][h3][lq];
            best = v0; int bc = 0;
            if (v1 < best) { best = v1; bc = 1; }
            if (v2 < best) { best = v2; bc = 2; }
            if (v3 < best) { best = v3; bc = 3; }
            if      (bc == 0) ++h0;
            else if (bc == 1) ++h1;
            else if (bc == 2) ++h2;
            else              ++h3;
        }
        gthr[q] = best * 1.0002f;   // conservative upper bound incl. fp margin
    }
}

__global__ __launch_bounds__(256) void aabb_kernel(const float* __restrict__ xp,
                                                   float* __restrict__ gaabb)
{
    __shared__ float wred[4][6];
    const int chunk = blockIdx.x;
    const int tid = threadIdx.x;
    const int j = chunk * CHSZ + tid;
    float mnx = xp[3*j+0], mny = xp[3*j+1], mnz = xp[3*j+2];
    float mxx = mnx, mxy = mny, mxz = mnz;
    for (int off = 32; off > 0; off >>= 1) {
        mnx = fminf(mnx, __shfl_down(mnx, off));
        mny = fminf(mny, __shfl_down(mny, off));
        mnz = fminf(mnz, __shfl_down(mnz, off));
        mxx = fmaxf(mxx, __shfl_down(mxx, off));
        mxy = fmaxf(mxy, __shfl_down(mxy, off));
        mxz = fmaxf(mxz, __shfl_down(mxz, off));
    }
    if ((tid & 63) == 0) {
        const int w = tid >> 6;
        wred[w][0]=mnx; wred[w][1]=mny; wred[w][2]=mnz;
        wred[w][3]=mxx; wred[w][4]=mxy; wred[w][5]=mxz;
    }
    __syncthreads();
    if (tid == 0) {
        float a0=wred[0][0], a1=wred[0][1], a2=wred[0][2];
        float a3=wred[0][3], a4=wred[0][4], a5=wred[0][5];
        for (int w = 1; w < 4; ++w) {
            a0=fminf(a0,wred[w][0]); a1=fminf(a1,wred[w][1]); a2=fminf(a2,wred[w][2]);
            a3=fmaxf(a3,wred[w][3]); a4=fmaxf(a4,wred[w][4]); a5=fmaxf(a5,wred[w][5]);
        }
        gaabb[chunk*8+0]=a0; gaabb[chunk*8+1]=a1; gaabb[chunk*8+2]=a2;
        gaabb[chunk*8+3]=a3; gaabb[chunk*8+4]=a4; gaabb[chunk*8+5]=a5;
    }
}

// ======================= KNN phase 1: per-chunk top-16 (wave-pruned) ============
__global__ __launch_bounds__(256) void knn_part(const float* __restrict__ x,
                                                const float* __restrict__ gthr,
                                                const float* __restrict__ gaabb,
                                                unsigned long long* __restrict__ parts)
{
    __shared__ __align__(16) float4 cpt[4 * CHSZ];        // per-wave copies, 16 KB
    __shared__ unsigned long long sbuf[256 * 9];          // 18.4 KB, stride 9

    const int tid   = threadIdx.x;
    const int wv    = tid >> 6;
    const int lane  = tid & 63;
    const int chunk = blockIdx.x & (NCH - 1);
    const int qg    = blockIdx.x >> 5;
    const int j0    = chunk * CHSZ;
    const int q     = qg * 256 + tid;

    const float qx = x[3*q+0], qy = x[3*q+1], qz = x[3*q+2];
    float thrF = gthr[q];

    {   // conservative chunk-skip: f32 AABB min-dist lower bound (x0.9998) vs thr
        const float dx = fmaxf(0.f, fmaxf(gaabb[chunk*8+0] - qx, qx - gaabb[chunk*8+3]));
        const float dy = fmaxf(0.f, fmaxf(gaabb[chunk*8+1] - qy, qy - gaabb[chunk*8+4]));
        const float dz = fmaxf(0.f, fmaxf(gaabb[chunk*8+2] - qz, qz - gaabb[chunk*8+5]));
        const float lb = fmaf(dx, dx, fmaf(dy, dy, dz*dz)) * 0.9998f;
        if (__all(lb > thrF)) {
#pragma unroll
            for (int r = 0; r < 16; ++r)
                parts[((size_t)chunk * KNB + r) * NPTS + q] = ~0ull;
            return;   // wave-uniform exit; kernel has no __syncthreads
        }
    }

    float4* wcpt = cpt + wv * CHSZ;
#pragma unroll
    for (int s = 0; s < 4; ++s) {
        const int j = lane + 64*s;
        wcpt[j] = make_float4(x[3*(j0+j)+0], x[3*(j0+j)+1], x[3*(j0+j)+2], 0.f);
    }

    unsigned long long bd[16];
#pragma unroll
    for (int r = 0; r < 16; ++r) bd[r] = ~0ull;
    int cnt = 0;
    unsigned long long* mybuf = sbuf + tid * 9;

    auto flush = [&]() {
#pragma unroll
        for (int s = 0; s < 8; ++s) {
            if (s < cnt) {
                const unsigned long long k = mybuf[s];
                if (k < bd[15]) {
#pragma unroll
                    for (int p2 = 15; p2 > 0; --p2) {
                        const bool sh = k < bd[p2-1];
                        const bool pl = k < bd[p2];
                        bd[p2] = sh ? bd[p2-1] : (pl ? k : bd[p2]);
                    }
                    if (k < bd[0]) bd[0] = k;
                }
            }
        }
        cnt = 0;
        if (bd[15] != ~0ull) {
            const double dub = __longlong_as_double((long long)(bd[15] | 8191ull));
            thrF = fminf(thrF, (float)dub * 1.0001f);
        }
    };

    for (int jj = 0; jj < CHSZ; jj += 4) {
        const float4 p0 = wcpt[jj+0];
        const float4 p1 = wcpt[jj+1];
        const float4 p2 = wcpt[jj+2];
        const float4 p3 = wcpt[jj+3];
#pragma unroll
        for (int u = 0; u < 4; ++u) {
            const float4 p = (u==0) ? p0 : (u==1) ? p1 : (u==2) ? p2 : p3;
            const float dx = qx - p.x, dy = qy - p.y, dz = qz - p.z;
            const float d2f = fmaf(dx, dx, fmaf(dy, dy, dz*dz));
            if (d2f <= thrF) {
                const double ddx = (double)dx, ddy = (double)dy, ddz = (double)dz;
                const double d2 = ddx*ddx + ddy*ddy + ddz*ddz;
                const unsigned long long key =
                    (((unsigned long long)__double_as_longlong(d2)) & ~8191ull)
                    | (unsigned long long)(j0 + jj + u);
                if (key < bd[15]) { mybuf[cnt] = key; ++cnt; }
            }
        }
        if (__any(cnt >= 5)) flush();
    }
    flush();

#pragma unroll
    for (int r = 0; r < 16; ++r)
        parts[((size_t)chunk * KNB + r) * NPTS + q] = bd[r];
}

// ======================= KNN phase 2: 32-way sorted merge =======================
__global__ __launch_bounds__(256) void knn_merge(const unsigned long long* __restrict__ parts,
                                                 int* __restrict__ idx_out)
{
    __shared__ unsigned char heads[256][NCH];
    const int tid = threadIdx.x;
    const int q = blockIdx.x * 256 + tid;
    unsigned char* h = heads[tid];
#pragma unroll
    for (int c = 0; c < NCH; ++c) h[c] = 0;
    for (int r = 0; r < KNB; ++r) {
        unsigned long long best = ~0ull; int bc = 0;
#pragma unroll
        for (int c = 0; c < NCH; ++c) {
            const unsigned long long k = parts[((size_t)c * KNB + h[c]) * NPTS + q];
            if (k < best) { best = k; bc = c; }
        }
        h[bc]++;
        idx_out[q*KNB + r] = (int)(best & 8191ull);
    }
}

// ======================= prep: Scol1/ScolU1 + Bcat_t = [W_t | W_t@U_t] ==========
__global__ __launch_bounds__(256) void prep_kernel(const float* __restrict__ kW,
                                                   const float* __restrict__ kU,
                                                   float* __restrict__ scol,
                                                   float* __restrict__ bcat)
{
    __shared__ float sW[64*64];
    __shared__ float sS[64];
    const int t = blockIdx.x;
    const int tid = threadIdx.x;
    if (t == 0) {
        for (int e = tid; e < 64*64; e += 256) sW[e] = kW[e];
        __syncthreads();
        if (tid < 64) {
            float s = 0.f;
            for (int j = 0; j < 64; ++j) s += sW[j*64 + tid];
            sS[tid] = s;
        }
        __syncthreads();
        if (tid < 64) {
            float s2 = 0.f;
            for (int j = 0; j < 64; ++j) s2 = fmaf(sS[j], kU[j*64 + tid], s2);
            scol[tid]      = sS[tid];
            scol[64 + tid] = s2;
        }
    } else {
        const float* W = kW + t*4096;
        const float* U = kU + t*4096;
        for (int e = tid; e < 64*64; e += 256) sW[e] = W[e];
        __syncthreads();
        float* B = bcat + (size_t)(t-1)*64*128;
        for (int o = tid; o < 64*64; o += 256) {
            const int j = o >> 6, c = o & 63;
            float s = 0.f;
            for (int l = 0; l < 64; ++l) s = fmaf(sW[j*64 + l], U[l*64 + c], s);
            B[j*128 + c]      = sW[j*64 + c];
            B[j*128 + 64 + c] = s;
        }
    }
}

// ======================= step1: rank-1 closed form =======================
__global__ __launch_bounds__(256) void step1_kernel(const float* __restrict__ xp,
                                                    const int* __restrict__ idxs,
                                                    const float* __restrict__ scol,
                                                    float* __restrict__ R1)
{
    const int pt = blockIdx.x * 256 + threadIdx.x;
    float mx0 = 0.f, mx1 = 0.f, mx2 = 0.f;
#pragma unroll
    for (int k = 0; k < KNB; ++k) {
        const int id = idxs[pt*KNB + k];
        mx0 += xp[3*id+0]; mx1 += xp[3*id+1]; mx2 += xp[3*id+2];
    }
    const float inv = 1.0f / KNB;
    mx0 *= inv; mx1 *= inv; mx2 *= inv;
    const float S2 = mx0*mx0 + mx1*mx1 + mx2*mx2;
    float* op = R1 + (size_t)pt * 192;
    for (int c = 0; c < 64; ++c) {
        const float sc = scol[c], su = scol[64 + c];
        const float dt = S2 * sc * su;
        const float dn = S2 * su * su;
        const float m  = (dt < 0.f) ? 0.8f * dt / (dn + VEPS) : 0.f;
        const float rc = fmaf(-m, su, sc);
        op[c]       = mx0 * rc;
        op[64 + c]  = mx1 * rc;
        op[128 + c] = mx2 * rc;
    }
}

// ======================= zgemm: YwZ = R @ Bcat (K=64, N=128) =======================
#define FMA4(ar, b0, b1, b2, b3, acc) \
    acc.x = fmaf(ar.x,b0.x, fmaf(ar.y,b1.x, fmaf(ar.z,b2.x, fmaf(ar.w,b3.x, acc.x)))); \
    acc.y = fmaf(ar.x,b0.y, fmaf(ar.y,b1.y, fmaf(ar.z,b2.y, fmaf(ar.w,b3.y, acc.y)))); \
    acc.z = fmaf(ar.x,b0.z, fmaf(ar.y,b1.z, fmaf(ar.z,b2.z, fmaf(ar.w,b3.z, acc.z)))); \
    acc.w = fmaf(ar.x,b0.w, fmaf(ar.y,b1.w, fmaf(ar.z,b2.w, fmaf(ar.w,b3.w, acc.w))));

__global__ __launch_bounds__(256) void zgemm_kernel(const float* __restrict__ R,
                                                    const float* __restrict__ Bcat,
                                                    float* __restrict__ YwZ)
{
    constexpr int SA = 68;
    __shared__ __align__(16) float sA[64*SA];
    __shared__ __align__(16) float sB[64*128];
    const int tid = threadIdx.x;
    const size_t row0 = (size_t)blockIdx.x * 64;

    for (int e4 = tid; e4 < 1024; e4 += 256) {
        const int r = e4 >> 4, c4 = (e4 & 15) * 4;
        *reinterpret_cast<float4*>(sA + r*SA + c4) =
            *reinterpret_cast<const float4*>(R + (row0 + r)*64 + c4);
    }
    for (int e4 = tid; e4 < 2048; e4 += 256) {
        const int j = e4 >> 5, c4 = (e4 & 31) * 4;
        *reinterpret_cast<float4*>(sB + j*128 + c4) =
            *reinterpret_cast<const float4*>(Bcat + j*128 + c4);
    }
    __syncthreads();

    const int rg = tid >> 5;
    const int d  = (tid & 31) * 4;
    float4 acc0={0,0,0,0},acc1=acc0,acc2=acc0,acc3=acc0,acc4=acc0,acc5=acc0,acc6=acc0,acc7=acc0;
    for (int c = 0; c < 64; c += 4) {
        const float4 b0 = *reinterpret_cast<const float4*>(sB + (c+0)*128 + d);
        const float4 b1 = *reinterpret_cast<const float4*>(sB + (c+1)*128 + d);
        const float4 b2 = *reinterpret_cast<const float4*>(sB + (c+2)*128 + d);
        const float4 b3 = *reinterpret_cast<const float4*>(sB + (c+3)*128 + d);
        float4 a;
        a = *reinterpret_cast<const float4*>(sA + (rg*8+0)*SA + c); FMA4(a,b0,b1,b2,b3,acc0);
        a = *reinterpret_cast<const float4*>(sA + (rg*8+1)*SA + c); FMA4(a,b0,b1,b2,b3,acc1);
        a = *reinterpret_cast<const float4*>(sA + (rg*8+2)*SA + c); FMA4(a,b0,b1,b2,b3,acc2);
        a = *reinterpret_cast<const float4*>(sA + (rg*8+3)*SA + c); FMA4(a,b0,b1,b2,b3,acc3);
        a = *reinterpret_cast<const float4*>(sA + (rg*8+4)*SA + c); FMA4(a,b0,b1,b2,b3,acc4);
        a = *reinterpret_cast<const float4*>(sA + (rg*8+5)*SA + c); FMA4(a,b0,b1,b2,b3,acc5);
        a = *reinterpret_cast<const float4*>(sA + (rg*8+6)*SA + c); FMA4(a,b0,b1,b2,b3,acc6);
        a = *reinterpret_cast<const float4*>(sA + (rg*8+7)*SA + c); FMA4(a,b0,b1,b2,b3,acc7);
    }
    float* op = YwZ + (row0 + rg*8)*128 + d;
    *reinterpret_cast<float4*>(op + 0*128) = acc0;
    *reinterpret_cast<float4*>(op + 1*128) = acc1;
    *reinterpret_cast<float4*>(op + 2*128) = acc2;
    *reinterpret_cast<float4*>(op + 3*128) = acc3;
    *reinterpret_cast<float4*>(op + 4*128) = acc4;
    *reinterpret_cast<float4*>(op + 5*128) = acc5;
    *reinterpret_cast<float4*>(op + 6*128) = acc6;
    *reinterpret_cast<float4*>(op + 7*128) = acc7;
}

// ======================= gather steps 2,3 (LDS-buf, sliding window) ==========
template<int PINP, int TT>
__global__ __launch_bounds__(256) void gather_kernel(
    const float* __restrict__ xp, const int* __restrict__ idxs,
    const float* __restrict__ yz,
    float* __restrict__ Rout,
    int ppb)
{
    constexpr int PCW = PINP * 128;
    constexpr int NSL = PCW / 4;
    constexpr int TC  = TT * 64;

    __shared__ __align__(16) float buf[TT * 128];
    __shared__ int   sIds[KNB];
    __shared__ float sXg[KNB*3];
    __shared__ float pdt[4][64], pdn[4][64], msc[64];

    const int tid   = threadIdx.x;
    const int slots = gridDim.x >> 3;
    const int xcd   = blockIdx.x & 7;
    const int slot  = blockIdx.x >> 3;
    const int base  = xcd * slots * ppb;

    for (int pi = 0; pi < ppb; ++pi) {
        const int pt = base + pi * slots + slot;
        if (tid < KNB) {
            const int id = idxs[pt*KNB + tid];
            sIds[tid] = id;
            sXg[tid*3+0] = xp[3*id+0];
            sXg[tid*3+1] = xp[3*id+1];
            sXg[tid*3+2] = xp[3*id+2];
        }
        __syncthreads();

        float xr[KNB*3];
#pragma unroll
        for (int e = 0; e < KNB*3; ++e) xr[e] = sXg[e];

        for (int sl = tid; sl < NSL; sl += 256) {
            const int b  = sl >> 5;
            const int cc = (sl & 31) * 4;
            float4 s0 = {0,0,0,0}, s1 = s0, s2 = s0;
#pragma unroll
            for (int k = 0; k < KNB; ++k) {
                const float4 val = *reinterpret_cast<const float4*>(
                    yz + (size_t)sIds[k]*PCW + b*128 + cc);
                const float xa = xr[k*3+0], xb = xr[k*3+1], xc = xr[k*3+2];
                s0.x=fmaf(xa,val.x,s0.x); s0.y=fmaf(xa,val.y,s0.y);
                s0.z=fmaf(xa,val.z,s0.z); s0.w=fmaf(xa,val.w,s0.w);
                s1.x=fmaf(xb,val.x,s1.x); s1.y=fmaf(xb,val.y,s1.y);
                s1.z=fmaf(xb,val.z,s1.z); s1.w=fmaf(xb,val.w,s1.w);
                s2.x=fmaf(xc,val.x,s2.x); s2.y=fmaf(xc,val.y,s2.y);
                s2.z=fmaf(xc,val.z,s2.z); s2.w=fmaf(xc,val.w,s2.w);
            }
            const float inv = 1.0f / KNB;
            s0.x*=inv; s0.y*=inv; s0.z*=inv; s0.w*=inv;
            s1.x*=inv; s1.y*=inv; s1.z*=inv; s1.w*=inv;
            s2.x*=inv; s2.y*=inv; s2.z*=inv; s2.w*=inv;
            *reinterpret_cast<float4*>(buf + (0*PINP + b)*128 + cc) = s0;
            *reinterpret_cast<float4*>(buf + (1*PINP + b)*128 + cc) = s1;
            *reinterpret_cast<float4*>(buf + (2*PINP + b)*128 + cc) = s2;
        }
        __syncthreads();
        {
            const int c = tid & 63, g = tid >> 6;
            float dt = 0.f, dn = 0.f;
            for (int t = g; t < TT; t += 4) {
                const float vv = buf[t*128 + c], dd = buf[t*128 + 64 + c];
                dt = fmaf(vv, dd, dt); dn = fmaf(dd, dd, dn);
            }
            pdt[g][c] = dt; pdn[g][c] = dn;
        }
        __syncthreads();
        if (tid < 64) {
            const float dt = pdt[0][tid]+pdt[1][tid]+pdt[2][tid]+pdt[3][tid];
            const float dn = pdn[0][tid]+pdn[1][tid]+pdn[2][tid]+pdn[3][tid];
            msc[tid] = (dt < 0.f) ? 0.8f * dt / (dn + VEPS) : 0.f;
        }
        __syncthreads();
        {
            float* op = Rout + (size_t)pt * TC;
            for (int e = tid; e < TC; e += 256) {
                const int t = e >> 6, c = e & 63;
                op[e] = fmaf(-msc[c], buf[t*128 + 64 + c], buf[t*128 + c]);
            }
        }
        __syncthreads();
    }
}

// ======================= gather step 4: channel-split + fused in-register dot ===
#define FMAQS(acc, s, val) \
    acc.x = fmaf(s, val.x, acc.x); acc.y = fmaf(s, val.y, acc.y); \
    acc.z = fmaf(s, val.z, acc.z); acc.w = fmaf(s, val.w, acc.w);

__global__ __launch_bounds__(256) void gather4_kernel(
    const float* __restrict__ xp, const int* __restrict__ idxs,
    const float* __restrict__ yz,      // NPTS x 3456
    const float* __restrict__ w4,
    float* __restrict__ hv, float* __restrict__ gpart,
    int ppb)
{
    constexpr int TT = 81;
    constexpr int CH = 32;
    constexpr int SB = 68;
    constexpr int NG = (TT*CH + 255) / 256;   // 11

    __shared__ __align__(16) float buf[TT * SB];
    __shared__ int   sIds[KNB];
    __shared__ float sXg[KNB*3];
    __shared__ float pdt[27][33], pdn[27][33];
    __shared__ float msc[CH];

    const int tid   = threadIdx.x;
    const int xcd   = blockIdx.x & 7;
    const int r2    = blockIdx.x >> 3;
    const int half  = r2 & 1;
    const int slot  = r2 >> 1;
    const int slots = gridDim.x >> 4;          // 128
    const int base0 = xcd * slots * ppb;
    const int c0    = half * CH;
    const int eff   = xcd * slots + slot;      // < 1024

    const int ub  = tid >> 3;
    const int ucq = tid & 7;
    const bool act = (ub < 27);
    const int srcV = ub*128 + c0 + ucq*4;
    const int srcD = srcV + 64;

    float gacc[NG];
#pragma unroll
    for (int i = 0; i < NG; ++i) gacc[i] = 0.f;

    for (int pi = 0; pi < ppb; ++pi) {
        const int pt = base0 + pi * slots + slot;
        if (tid < KNB) {
            const int id = idxs[pt*KNB + tid];
            sIds[tid] = id;
            sXg[tid*3+0] = xp[3*id+0];
            sXg[tid*3+1] = xp[3*id+1];
            sXg[tid*3+2] = xp[3*id+2];
        }
        __syncthreads();

        if (act) {
            float4 vA[3], dA[3];
#pragma unroll
            for (int a = 0; a < 3; ++a) { vA[a] = make_float4(0,0,0,0); dA[a] = vA[a]; }
#pragma unroll
            for (int k = 0; k < KNB; ++k) {
                const float* rowp = yz + (size_t)sIds[k]*3456;
                const float4 vq = *reinterpret_cast<const float4*>(rowp + srcV);
                const float4 dq = *reinterpret_cast<const float4*>(rowp + srcD);
                const float xa = sXg[k*3+0], xb = sXg[k*3+1], xc = sXg[k*3+2];
                FMAQS(vA[0], xa, vq) FMAQS(vA[1], xb, vq) FMAQS(vA[2], xc, vq)
                FMAQS(dA[0], xa, dq) FMAQS(dA[1], xb, dq) FMAQS(dA[2], xc, dq)
            }
            const float inv = 1.0f / KNB;
            float4 dt4 = make_float4(0,0,0,0), dn4 = dt4;
#pragma unroll
            for (int a = 0; a < 3; ++a) {
                vA[a].x*=inv; vA[a].y*=inv; vA[a].z*=inv; vA[a].w*=inv;
                dA[a].x*=inv; dA[a].y*=inv; dA[a].z*=inv; dA[a].w*=inv;
                dt4.x = fmaf(vA[a].x, dA[a].x, dt4.x);
                dt4.y = fmaf(vA[a].y, dA[a].y, dt4.y);
                dt4.z = fmaf(vA[a].z, dA[a].z, dt4.z);
                dt4.w = fmaf(vA[a].w, dA[a].w, dt4.w);
                dn4.x = fmaf(dA[a].x, dA[a].x, dn4.x);
                dn4.y = fmaf(dA[a].y, dA[a].y, dn4.y);
                dn4.z = fmaf(dA[a].z, dA[a].z, dn4.z);
                dn4.w = fmaf(dA[a].w, dA[a].w, dn4.w);
                float* bp = buf + (a*27 + ub)*SB;
                *reinterpret_cast<float4*>(bp + ucq*4)      = vA[a];
                *reinterpret_cast<float4*>(bp + 32 + ucq*4) = dA[a];
            }
            pdt[ub][ucq*4+0] = dt4.x; pdt[ub][ucq*4+1] = dt4.y;
            pdt[ub][ucq*4+2] = dt4.z; pdt[ub][ucq*4+3] = dt4.w;
            pdn[ub][ucq*4+0] = dn4.x; pdn[ub][ucq*4+1] = dn4.y;
            pdn[ub][ucq*4+2] = dn4.z; pdn[ub][ucq*4+3] = dn4.w;
        }
        __syncthreads();
        if (tid < CH) {
            float dt = 0.f, dn = 0.f;
#pragma unroll
            for (int b2 = 0; b2 < 27; ++b2) { dt += pdt[b2][tid]; dn += pdn[b2][tid]; }
            msc[tid] = (dt < 0.f) ? 0.8f * dt / (dn + VEPS) : 0.f;
        }
        __syncthreads();
#pragma unroll
        for (int i = 0; i < NG; ++i) {
            const int e = i*256 + tid;
            if (e < TT*CH) {
                const int t = e >> 5, cc = e & 31;
                const float v = fmaf(-msc[cc], buf[t*SB + 32 + cc], buf[t*SB + cc]);
                buf[t*SB + cc] = v;
                gacc[i] += v;
            }
        }
        __syncthreads();
        for (int e = tid; e < 9*CH; e += 256) {
            const int pq = e >> 5, cc = e & 31;
            const int p = pq / 3, qq = pq - 3*p;
            const int c = c0 + cc;
            float tr0=0,tr1=0,tr2=0,tr3=0,tr4=0,tr5=0;
#pragma unroll
            for (int r = 0; r < 3; ++r) {
                tr0 += buf[(r*36 + p*3 + qq )*SB + cc];
                tr1 += buf[(r*30 + p*9 + qq )*SB + cc];
                tr2 += buf[(r*28 + p*9 + qq*3)*SB + cc];
                tr3 += buf[(p*27 + r*12 + qq )*SB + cc];
                tr4 += buf[(p*27 + r*10 + qq*3)*SB + cc];
                tr5 += buf[(p*27 + qq*9 + r*4 )*SB + cc];
            }
            hv[(size_t)pt*576 + pq*64 + c] =
                  w4[0*C2 + c]*tr0 + w4[1*C2 + c]*tr1 + w4[2*C2 + c]*tr2
                + w4[3*C2 + c]*tr3 + w4[4*C2 + c]*tr4 + w4[5*C2 + c]*tr5;
        }
        __syncthreads();
    }
    float* gp = gpart + (size_t)eff * 5184;
#pragma unroll
    for (int i = 0; i < NG; ++i) {
        const int e = i*256 + tid;
        if (e < TT*CH) {
            const int t = e >> 5, cc = e & 31;
            gp[t*64 + c0 + cc] = gacc[i];
        }
    }
}

// ======================= g reduction (1024 parts) =======================
__global__ __launch_bounds__(256) void reduce_g_kernel(const float* __restrict__ gpart,
                                                       float* __restrict__ g)
{
    __shared__ float red[256];
    const int el = threadIdx.x & 15, pg = threadIdx.x >> 4;
    const int e = blockIdx.x * 16 + el;
    float s = 0.f;
    for (int p = pg; p < 1024; p += 16) s += gpart[(size_t)p * (81*C1) + e];
    red[threadIdx.x] = s;
    __syncthreads();
    for (int st = 8; st > 0; st >>= 1) {
        if (pg < st) red[el + 16*pg] += red[el + 16*(pg+st)];
        __syncthreads();
    }
    if (pg == 0) g[e] = red[el] * (1.0f/NPTS);
}

// ======================= hg + hgW precompute =======================
__global__ __launch_bounds__(256) void hgw_kernel(const float* __restrict__ g,
                                                  const float* __restrict__ w4,
                                                  const float* __restrict__ cW,
                                                  float* __restrict__ hgW)
{
    __shared__ float gs[81*C1];
    __shared__ float hg[9*C1];
    const int tid = threadIdx.x;
    for (int e = tid; e < 81*C1; e += 256) gs[e] = g[e];
    __syncthreads();
    for (int e = tid; e < 9*C1; e += 256) {
        const int pq = e >> 6, c = e & 63;
        const int p = pq / 3, qq = pq - 3*p;
        float tr0=0,tr1=0,tr2=0,tr3=0,tr4=0,tr5=0;
#pragma unroll
        for (int r = 0; r < 3; ++r) {
            tr0 += gs[(r*36 + p*3 + qq ) * C1 + c];
            tr1 += gs[(r*30 + p*9 + qq ) * C1 + c];
            tr2 += gs[(r*28 + p*9 + qq*3) * C1 + c];
            tr3 += gs[(p*27 + r*12 + qq ) * C1 + c];
            tr4 += gs[(p*27 + r*10 + qq*3) * C1 + c];
            tr5 += gs[(p*27 + qq*9 + r*4 ) * C1 + c];
        }
        hg[e] = w4[0*C2 + 64 + c]*tr0 + w4[1*C2 + 64 + c]*tr1 + w4[2*C2 + 64 + c]*tr2
              + w4[3*C2 + 64 + c]*tr3 + w4[4*C2 + 64 + c]*tr4 + w4[5*C2 + 64 + c]*tr5;
    }
    __syncthreads();
    for (int o = tid; o < 9*C2; o += 256) {
        const int t = o >> 7, c = o & 127;
        float s = 0.f;
        for (int j = 0; j < C1; ++j) s = fmaf(hg[t*C1 + j], cW[(C1+j)*C2 + c], s);
        hgW[o] = s;
    }
}

// ======================= contraction head =======================
__global__ __launch_bounds__(256) void contract_kernel(const float* __restrict__ hv,
                                                       const float* __restrict__ hgW,
                                                       const float* __restrict__ cW,
                                                       const float* __restrict__ cU,
                                                       const float* __restrict__ w2,
                                                       const int* __restrict__ perm,
                                                       float* __restrict__ out,
                                                       int ppb)
{
    constexpr int S0 = C1 + 4;
    constexpr int SH = C2 + 4;
    __shared__ __align__(16) float h0[36*S0];
    __shared__ __align__(16) float h1[36*SH];
    __shared__ __align__(16) float h2[36*SH];
    __shared__ __align__(16) float hgs[9*C2];
    __shared__ int sPerm[4];

    const int tid = threadIdx.x;
    for (int e = tid; e < 9*C2; e += 256) hgs[e] = hgW[e];
    __syncthreads();

    const int iters = ppb >> 2;
    for (int it = 0; it < iters; ++it) {
        const int base = blockIdx.x * ppb + it * 4;
        if (tid < 4) sPerm[tid] = perm[base + tid];
        for (int e = tid; e < 4*9*C1; e += 256) {
            const int pt = e / 576, rem = e - pt*576;
            const int t = rem >> 6, c = rem & 63;
            h0[(pt*9 + t)*S0 + c] = hv[(size_t)(base+pt)*576 + rem];
        }
        __syncthreads();
        for (int u = tid; u < 9*32; u += 256) {
            const int tg = u >> 5;
            const int d  = (u & 31) * 4;
            const int r0 = tg*4;
            float4 acc0 = *reinterpret_cast<const float4*>(hgs + ((r0+0)%9)*C2 + d);
            float4 acc1 = *reinterpret_cast<const float4*>(hgs + ((r0+1)%9)*C2 + d);
            float4 acc2 = *reinterpret_cast<const float4*>(hgs + ((r0+2)%9)*C2 + d);
            float4 acc3 = *reinterpret_cast<const float4*>(hgs + ((r0+3)%9)*C2 + d);
            for (int c = 0; c < C1; c += 4) {
                const float4 a0 = *reinterpret_cast<const float4*>(h0 + (r0+0)*S0 + c);
                const float4 a1 = *reinterpret_cast<const float4*>(h0 + (r0+1)*S0 + c);
                const float4 a2 = *reinterpret_cast<const float4*>(h0 + (r0+2)*S0 + c);
                const float4 a3 = *reinterpret_cast<const float4*>(h0 + (r0+3)*S0 + c);
                const float4 b0 = *reinterpret_cast<const float4*>(cW + (c+0)*C2 + d);
                const float4 b1 = *reinterpret_cast<const float4*>(cW + (c+1)*C2 + d);
                const float4 b2 = *reinterpret_cast<const float4*>(cW + (c+2)*C2 + d);
                const float4 b3 = *reinterpret_cast<const float4*>(cW + (c+3)*C2 + d);
                FMA4(a0, b0, b1, b2, b3, acc0);
                FMA4(a1, b0, b1, b2, b3, acc1);
                FMA4(a2, b0, b1, b2, b3, acc2);
                FMA4(a3, b0, b1, b2, b3, acc3);
            }
            *reinterpret_cast<float4*>(h1 + (r0+0)*SH + d) = acc0;
            *reinterpret_cast<float4*>(h1 + (r0+1)*SH + d) = acc1;
            *reinterpret_cast<float4*>(h1 + (r0+2)*SH + d) = acc2;
            *reinterpret_cast<float4*>(h1 + (r0+3)*SH + d) = acc3;
        }
        __syncthreads();
        for (int u = tid; u < 9*32; u += 256) {
            const int tg = u >> 5;
            const int d  = (u & 31) * 4;
            const int r0 = tg*4;
            float4 acc0 = {0,0,0,0}, acc1 = acc0, acc2 = acc0, acc3 = acc0;
            for (int c = 0; c < C2; c += 4) {
                const float4 a0 = *reinterpret_cast<const float4*>(h1 + (r0+0)*SH + c);
                const float4 a1 = *reinterpret_cast<const float4*>(h1 + (r0+1)*SH + c);
                const float4 a2 = *reinterpret_cast<const float4*>(h1 + (r0+2)*SH + c);
                const float4 a3 = *reinterpret_cast<const float4*>(h1 + (r0+3)*SH + c);
                const float4 b0 = *reinterpret_cast<const float4*>(cU + (c+0)*C2 + d);
                const float4 b1 = *reinterpret_cast<const float4*>(cU + (c+1)*C2 + d);
                const float4 b2 = *reinterpret_cast<const float4*>(cU + (c+2)*C2 + d);
                const float4 b3 = *reinterpret_cast<const float4*>(cU + (c+3)*C2 + d);
                FMA4(a0, b0, b1, b2, b3, acc0);
                FMA4(a1, b0, b1, b2, b3, acc1);
                FMA4(a2, b0, b1, b2, b3, acc2);
                FMA4(a3, b0, b1, b2, b3, acc3);
            }
            *reinterpret_cast<float4*>(h2 + (r0+0)*SH + d) = acc0;
            *reinterpret_cast<float4*>(h2 + (r0+1)*SH + d) = acc1;
            *reinterpret_cast<float4*>(h2 + (r0+2)*SH + d) = acc2;
            *reinterpret_cast<float4*>(h2 + (r0+3)*SH + d) = acc3;
        }
        __syncthreads();
#pragma unroll
        for (int p2 = 0; p2 < 2; ++p2) {
            const int pair = tid + 256*p2;
            const int pt = pair >> 7, c = pair & 127;
            float dt = 0.f, dn = 0.f;
            for (int t = 0; t < 9; ++t) {
                const float vv = h1[(pt*9+t)*SH + c], dd = h2[(pt*9+t)*SH + c];
                dt = fmaf(vv, dd, dt); dn = fmaf(dd, dd, dn);
            }
            const float m = (dt < 0.f) ? 0.8f * dt / (dn + VEPS) : 0.f;
            float s = 0.f;
#pragma unroll
            for (int r = 0; r < 3; ++r) {
                const int t = r * 4;
                s += fmaf(-m, h2[(pt*9+t)*SH + c], h1[(pt*9+t)*SH + c]);
            }
            out[(size_t)sPerm[pt]*C2 + c] = w2[c] * s;
        }
        __syncthreads();
    }
}

// ======================= launcher =======================
extern "C" void kernel_launch(void* const* d_in, const int* in_sizes, int n_in,
                              void* d_out, int out_size, void* d_ws, size_t ws_size,
                              hipStream_t stream)
{
    (void)in_sizes; (void)n_in; (void)out_size; (void)ws_size;
    const float* x  = (const float*)d_in[0];
    const float* kW = (const float*)d_in[1];
    const float* kU = (const float*)d_in[2];
    const float* w4 = (const float*)d_in[3];
    const float* cW = (const float*)d_in[4];
    const float* cU = (const float*)d_in[5];
    const float* w2 = (const float*)d_in[6];
    float* out = (float*)d_out;

    char* ws = (char*)d_ws;
    size_t off = 0;
    auto alloc = [&](size_t bytes) -> void* {
        void* p = ws + off; off += (bytes + 255) & ~(size_t)255; return p;
    };
    int*   idx   = (int*)  alloc((size_t)NPTS*KNB*4);
    float* xp    = (float*)alloc((size_t)NPTS*3*4);
    unsigned long long* keys = (unsigned long long*)alloc((size_t)NPTS*8);
    int*   perm  = (int*)  alloc((size_t)NPTS*4);
    int*   rk    = (int*)  alloc((size_t)NPTS*4);
    float* gthr  = (float*)alloc((size_t)NPTS*4);
    float* gaabb = (float*)alloc((size_t)NCH*8*4);
    float* scol  = (float*)alloc(128*4);
    float* bcat  = (float*)alloc((size_t)3*64*128*4);
    float* R1    = (float*)alloc((size_t)NPTS*3*C1*4);      // hv alias (spans into YwZ2)
    float* YwZ2  = (float*)alloc((size_t)NPTS*3*C2*4);
    float* R2    = (float*)alloc((size_t)NPTS*9*C1*4);      // gpart alias (spans into YwZ3)
    float* YwZ3  = (float*)alloc((size_t)NPTS*9*C2*4);
    float* R3    = (float*)alloc((size_t)NPTS*27*C1*4);
    float* YwZ4  = (float*)alloc((size_t)NPTS*27*C2*4);
    float* g     = (float*)alloc((size_t)81*C1*4);
    float* hgW   = (float*)alloc((size_t)9*C2*4);

    float* hv    = R1;
    float* gpart = R2;
    unsigned long long* parts = (unsigned long long*)YwZ4;  // dead before zgemm4

    keys_kernel <<<NPTS/256, 256, 0, stream>>>(x, keys);
    rank_zero   <<<NPTS/256, 256, 0, stream>>>(rk);
    rank_part   <<<256, 256, 0, stream>>>(keys, rk);
    rank_scatter<<<NPTS/256, 256, 0, stream>>>(rk, x, xp, perm);
    ownthr_kernel<<<NPTS/64, 256, 0, stream>>>(xp, gthr);
    aabb_kernel <<<NCH, 256, 0, stream>>>(xp, gaabb);
    knn_part    <<<32*NCH, 256, 0, stream>>>(xp, gthr, gaabb, parts);
    knn_merge   <<<NPTS/256, 256, 0, stream>>>(parts, idx);
    prep_kernel <<<4, 256, 0, stream>>>(kW, kU, scol, bcat);
    step1_kernel<<<NPTS/256, 256, 0, stream>>>(xp, idx, scol, R1);

    zgemm_kernel<<<NPTS*3/64,  256, 0, stream>>>(R1, bcat,            YwZ2);
    gather_kernel<3, 9>  <<<2048, 256, 0, stream>>>(xp, idx, YwZ2, R2, 4);
    zgemm_kernel<<<NPTS*9/64,  256, 0, stream>>>(R2, bcat + 8192,     YwZ3);
    gather_kernel<9, 27> <<<2048, 256, 0, stream>>>(xp, idx, YwZ3, R3, 4);
    zgemm_kernel<<<NPTS*27/64, 256, 0, stream>>>(R3, bcat + 16384,    YwZ4);
    gather4_kernel<<<2048, 256, 0, stream>>>(xp, idx, YwZ4, w4, hv, gpart, 8);

    reduce_g_kernel<<<324, 256, 0, stream>>>(gpart, g);
    hgw_kernel<<<1, 256, 0, stream>>>(g, w4, cW, hgW);
    contract_kernel<<<1024, 256, 0, stream>>>(hv, hgW, cW, cU, w2, perm, out, 8);
}